// Round 6
// baseline (6521.719 us; speedup 1.0000x reference)
//
#include <hip/hip_runtime.h>
#include <math.h>

// Seq2seq decoder w/ location-aware attention. H=512 V=64 B=32 L=2048 T=32.
// All f32 (greedy argmax feedback must track numpy; bf16 flips preds -> fail).
//
// R6: interleaved VE[b][l][{vp,enc}][512] sweep stream (one contiguous 4KB
// line per (b,l) instead of vp-contig + enc-strided-64KB); gates GEMM + LSTM
// cell re-fused (drops gates round-trip + 1 launch). ws_size-guarded fallback
// to the R5 two-stream sweep if scratch < 275MB.
// Per step (6 kernels):
//  1 k_gatecell (32 blk):  gates = hprev@W_hh^T + embW[curin]; cell -> hnew,cbuf
//  2 k_matT16 m1 (32 blk): q2 = hnew @ Wq^T + (conv_b+attn_bias)
//  3 k_sctx   (2048 blk):  per (b,32-l chunk): score->Scur + partial ctx
//  4 k_hcat   (32 blk):    ctx reduce + [h|ctx] row build
//  5 k_matT16 m3 (32 blk): co = tanh(hcat @ W_concat^T + b_concat)
//  6 k_out2   (32 blk):    logits/softmax/argmax/CE

#define Hdim 512
#define Vdim 64
#define Bdim 32
#define Ldim 2048
#define Tdim 32
#define CLEN 32
#define NCH 64

__device__ __forceinline__ float sigmoid_f(float x) {
  return 1.0f / (1.0f + __expf(-x));
}
__device__ __forceinline__ float tanh_f(float x) {
  float ax = fabsf(x);
  float e = __expf(2.0f * ax);
  float r = 1.0f - 2.0f / (e + 1.0f);
  return copysignf(r, x);
}

// ---------------------------------------------------------------- init
__global__ void k_init(const int* __restrict__ init_in, const float* __restrict__ h0,
                       const float* __restrict__ c0, float* __restrict__ h,
                       float* __restrict__ c, float* __restrict__ Sprev,
                       float* __restrict__ ssum, int* __restrict__ curin,
                       float* __restrict__ lossb) {
  int i = blockIdx.x * blockDim.x + threadIdx.x;
  if (i < Bdim * Hdim) { h[i] = h0[i]; c[i] = c0[i]; }
  if (i < Bdim * Ldim) Sprev[i] = 0.0f;
  if (i < Bdim) { ssum[32 + i] = 1.0f; curin[i] = init_in[i]; }
  if (i == 0) lossb[0] = 0.0f;
}

__global__ void k_pack(const float* __restrict__ conv_w, const float* __restrict__ conv_b,
                       const float* __restrict__ attn_bias, const float* __restrict__ Ws,
                       float4* __restrict__ P4, float* __restrict__ cbab) {
  int h = blockIdx.x * blockDim.x + threadIdx.x;
  if (h < Hdim) {
    P4[h] = make_float4(conv_w[3 * h], conv_w[3 * h + 1], conv_w[3 * h + 2], Ws[h]);
    cbab[h] = conv_b[h] + attn_bias[h];
  }
}

__global__ void k_transpose(const float* __restrict__ in, float* __restrict__ out,
                            int R, int C) {
  int i = blockIdx.x * blockDim.x + threadIdx.x;
  if (i < R * C) { int r = i / C, c = i % C; out[(size_t)c * R + r] = in[i]; }
}

// copy enc[(l*B+b)*512 + h] -> VE[(b*L+l)*1024 + 512 + h]; 128 thr, 1 row/blk
__global__ void k_copyenc(const float* __restrict__ enc, float* __restrict__ VE) {
  const int r = blockIdx.x;               // r = l*B + b
  const int b = r & (Bdim - 1);
  const int l = r >> 5;
  const float4 v = *(const float4*)(enc + (size_t)r * Hdim + threadIdx.x * 4);
  *(float4*)(VE + ((size_t)b * Ldim + l) * 1024 + 512 + threadIdx.x * 4) = v;
}

// ---------------------------------------------------------------- 32m x 16n GEMM
// m1: +ex1[n]  m2: +ex1[n]+ex2[n]  m3: tanh(+ex1[n])
__global__ __launch_bounds__(256) void k_matT16(
    const float* __restrict__ A, const float* __restrict__ W,
    float* __restrict__ out, int Kdim, int Ntot, int mode,
    const float* __restrict__ ex1, const float* __restrict__ ex2) {
  __shared__ float a_lds[64][33];
  __shared__ float w_lds[64][17];
  const int tid = threadIdx.x;
  const int n0 = blockIdx.x * 16;
  const int m0 = blockIdx.y * 32;
  const int tm = tid >> 3;
  const int tn = tid & 7;
  float acc0 = 0.f, acc1 = 0.f;
  for (int k0 = 0; k0 < Kdim; k0 += 64) {
    {
      const int m = tid & 31, kg = tid >> 5;
      const float* ap = A + (size_t)(m0 + m) * Kdim + k0 + kg * 8;
      float4 v0 = *(const float4*)ap;
      float4 v1 = *(const float4*)(ap + 4);
      const int kk = kg * 8;
      a_lds[kk + 0][m] = v0.x; a_lds[kk + 1][m] = v0.y;
      a_lds[kk + 2][m] = v0.z; a_lds[kk + 3][m] = v0.w;
      a_lds[kk + 4][m] = v1.x; a_lds[kk + 5][m] = v1.y;
      a_lds[kk + 6][m] = v1.z; a_lds[kk + 7][m] = v1.w;
    }
    if (tid < 128) {
      const int r = tid & 15, kg = tid >> 4;
      const float* wp = W + (size_t)(n0 + r) * Kdim + k0 + kg * 8;
      float4 v0 = *(const float4*)wp;
      float4 v1 = *(const float4*)(wp + 4);
      const int kk = kg * 8;
      w_lds[kk + 0][r] = v0.x; w_lds[kk + 1][r] = v0.y;
      w_lds[kk + 2][r] = v0.z; w_lds[kk + 3][r] = v0.w;
      w_lds[kk + 4][r] = v1.x; w_lds[kk + 5][r] = v1.y;
      w_lds[kk + 6][r] = v1.z; w_lds[kk + 7][r] = v1.w;
    }
    __syncthreads();
#pragma unroll 16
    for (int kk = 0; kk < 64; kk++) {
      const float a = a_lds[kk][tm];
      acc0 += a * w_lds[kk][tn * 2];
      acc1 += a * w_lds[kk][tn * 2 + 1];
    }
    __syncthreads();
  }
  const int gm = m0 + tm;
#pragma unroll
  for (int c = 0; c < 2; c++) {
    const int n = n0 + tn * 2 + c;
    const float a = (c == 0) ? acc0 : acc1;
    float r;
    if (mode == 1)      r = a + ex1[n];
    else if (mode == 2) r = a + ex1[n] + ex2[n];
    else                r = tanh_f(a + ex1[n]);
    out[(size_t)gm * Ntot + n] = r;
  }
}

// ---------------------------------------------------------------- v_proj GEMM
// writes rows with stride ostride (1024 when filling VE, else 512)
__global__ __launch_bounds__(256) void k_vproj(const float* __restrict__ enc,
                                               const float* __restrict__ Wv,
                                               float* __restrict__ vp, int ostride) {
  __shared__ float At[8][128];
  __shared__ float Bt[8][128];
  const int tid = threadIdx.x;
  const int r0 = blockIdx.x * 128;
  const int c0 = blockIdx.y * 128;
  const int tx = tid & 15;
  const int ty = tid >> 4;
  float acc[8][8];
#pragma unroll
  for (int i = 0; i < 8; i++)
#pragma unroll
    for (int j = 0; j < 8; j++) acc[i][j] = 0.f;

  for (int k0 = 0; k0 < Hdim; k0 += 8) {
    {
      const int r = tid & 127;
      const int kg = tid >> 7;
      const int gr = r0 + r;
      const int b = gr >> 11;
      const int l = gr & (Ldim - 1);
      const float* ap = enc + ((size_t)l * Bdim + b) * Hdim + k0 + kg * 4;
      float4 v = *(const float4*)ap;
      At[kg * 4 + 0][r] = v.x; At[kg * 4 + 1][r] = v.y;
      At[kg * 4 + 2][r] = v.z; At[kg * 4 + 3][r] = v.w;
      const float* wp = Wv + (size_t)(c0 + r) * Hdim + k0 + kg * 4;
      float4 w = *(const float4*)wp;
      Bt[kg * 4 + 0][r] = w.x; Bt[kg * 4 + 1][r] = w.y;
      Bt[kg * 4 + 2][r] = w.z; Bt[kg * 4 + 3][r] = w.w;
    }
    __syncthreads();
#pragma unroll
    for (int kk = 0; kk < 8; kk++) {
      float a[8], bb[8];
      *(float4*)&a[0] = *(const float4*)&At[kk][ty * 8];
      *(float4*)&a[4] = *(const float4*)&At[kk][ty * 8 + 4];
      *(float4*)&bb[0] = *(const float4*)&Bt[kk][tx * 4];
      *(float4*)&bb[4] = *(const float4*)&Bt[kk][64 + tx * 4];
#pragma unroll
      for (int i = 0; i < 8; i++)
#pragma unroll
        for (int j = 0; j < 8; j++) acc[i][j] += a[i] * bb[j];
    }
    __syncthreads();
  }
#pragma unroll
  for (int i = 0; i < 8; i++) {
    float* orow = vp + (size_t)(r0 + ty * 8 + i) * ostride + c0;
    float4 o0 = {acc[i][0], acc[i][1], acc[i][2], acc[i][3]};
    float4 o1 = {acc[i][4], acc[i][5], acc[i][6], acc[i][7]};
    *(float4*)(orow + tx * 4) = o0;
    *(float4*)(orow + 64 + tx * 4) = o1;
  }
}

// ---------------------------------------------------------------- gates GEMM + LSTM cell
// 32 blocks x 16 h-cols; all 4 gates per block; epilogue applies the cell.
__global__ __launch_bounds__(256) void k_gatecell(
    const float* __restrict__ hprev, const float* __restrict__ W_hh,
    const float* __restrict__ embW, const int* __restrict__ curin,
    float* __restrict__ hnew, float* __restrict__ cbuf,
    float* __restrict__ ssum_zero) {
  __shared__ float a_lds[32][68];
  __shared__ float w_lds[4][16][68];
  const int tid = threadIdx.x;
  const int n0 = blockIdx.x * 16;
  if (blockIdx.x == 0 && tid < Bdim) ssum_zero[tid] = 0.f;
  const int tm = tid >> 3;
  const int tn = tid & 7;
  float acc[4][2] = {};
  for (int k0 = 0; k0 < Hdim; k0 += 64) {
    {
      const int m = tid & 31, kg = tid >> 5;
      const float* ap = hprev + (size_t)m * Hdim + k0 + kg * 8;
      float4 v0 = *(const float4*)ap, v1 = *(const float4*)(ap + 4);
      *(float4*)&a_lds[m][kg * 8] = v0;
      *(float4*)&a_lds[m][kg * 8 + 4] = v1;
    }
    {
      const int g = tid >> 6, r = (tid >> 2) & 15, kq = tid & 3;
      const float* wp = W_hh + (size_t)(g * Hdim + n0 + r) * Hdim + k0 + kq * 16;
#pragma unroll
      for (int q = 0; q < 4; q++) {
        float4 v = *(const float4*)(wp + q * 4);
        *(float4*)&w_lds[g][r][kq * 16 + q * 4] = v;
      }
    }
    __syncthreads();
#pragma unroll
    for (int kk = 0; kk < 64; kk += 4) {
      float4 a4 = *(const float4*)&a_lds[tm][kk];
#pragma unroll
      for (int g = 0; g < 4; g++) {
        float4 w0 = *(const float4*)&w_lds[g][tn * 2][kk];
        float4 w1 = *(const float4*)&w_lds[g][tn * 2 + 1][kk];
        acc[g][0] += a4.x * w0.x + a4.y * w0.y + a4.z * w0.z + a4.w * w0.w;
        acc[g][1] += a4.x * w1.x + a4.y * w1.y + a4.z * w1.z + a4.w * w1.w;
      }
    }
    __syncthreads();
  }
  const int m = tm;
  const float* ew = embW + (size_t)curin[m] * 2048;
#pragma unroll
  for (int c = 0; c < 2; c++) {
    const int n = n0 + tn * 2 + c;
    const float gi = acc[0][c] + ew[n];
    const float gf = acc[1][c] + ew[512 + n];
    const float gg = acc[2][c] + ew[1024 + n];
    const float go = acc[3][c] + ew[1536 + n];
    const float cn = sigmoid_f(gf) * cbuf[(size_t)m * Hdim + n] + sigmoid_f(gi) * tanh_f(gg);
    const float hn = sigmoid_f(go) * tanh_f(cn);
    cbuf[(size_t)m * Hdim + n] = cn;
    hnew[(size_t)m * Hdim + n] = hn;
  }
}

// ---------------------------------------------------------------- fused score+ctx sweep
// mode1 (VE): one contiguous 4KB line per (b,l): [vp row | enc row].
// mode0: vp contiguous + enc strided (fallback).
__global__ __launch_bounds__(256) void k_sctx(
    const float* __restrict__ vbase, const float* __restrict__ ebase,
    const float* __restrict__ q2, const float* __restrict__ Sprev,
    const float* __restrict__ ssum_prev, const float4* __restrict__ P4,
    const float* __restrict__ bs, float* __restrict__ Scur,
    float* __restrict__ ssum_cur, float* __restrict__ pctx, int mode) {
  __shared__ float pad[4][512];
  __shared__ float wsum[4];
  const int chunk = blockIdx.x & (NCH - 1);
  const int b = blockIdx.x >> 6;
  const int tid = threadIdx.x;
  const int wave = tid >> 6, lane = tid & 63;
  const int l0 = chunk * CLEN + wave * 8;

  float4 pp[8];
#pragma unroll
  for (int e = 0; e < 8; e++) pp[e] = P4[lane * 8 + e];
  float qv[8];
  {
    const float* qrow = q2 + (size_t)b * Hdim + lane * 8;
    *(float4*)&qv[0] = *(const float4*)qrow;
    *(float4*)&qv[4] = *(const float4*)(qrow + 4);
  }
  const float inv = 1.0f / ssum_prev[b];
  const float* sp = Sprev + (size_t)b * Ldim;
  const float bsv = bs[0];

  float acc[8];
#pragma unroll
  for (int e = 0; e < 8; e++) acc[e] = 0.f;
  float csum = 0.f;

#pragma unroll 2
  for (int i = 0; i < 8; i++) {
    const int l = l0 + i;
    const float* vrow;
    const float* erow;
    if (mode) {
      vrow = vbase + ((size_t)b * Ldim + l) * 1024 + lane * 8;
      erow = vrow + 512;
    } else {
      vrow = vbase + ((size_t)b * Ldim + l) * 512 + lane * 8;
      erow = ebase + ((size_t)l * Bdim + b) * 512 + lane * 8;
    }
    float vv[8];
    *(float4*)&vv[0] = *(const float4*)vrow;
    *(float4*)&vv[4] = *(const float4*)(vrow + 4);
    const float4 e0 = *(const float4*)erow;
    const float4 e1 = *(const float4*)(erow + 4);
    const float a0 = (l > 0) ? sp[l - 1] * inv : 0.f;
    const float a1 = sp[l] * inv;
    const float a2 = (l < Ldim - 1) ? sp[l + 1] * inv : 0.f;
    float s = 0.f;
#pragma unroll
    for (int e = 0; e < 8; e++) {
      float x = vv[e] + qv[e] + pp[e].x * a0 + pp[e].y * a1 + pp[e].z * a2;
      s += pp[e].w * tanh_f(x);
    }
#pragma unroll
    for (int off = 32; off; off >>= 1) s += __shfl_xor(s, off, 64);
    const float sg = 1.0f / (1.0f + __expf(-(s + bsv)));
    csum += sg;
    if (lane == 0) Scur[(size_t)b * Ldim + l] = sg;
    acc[0] += sg * e0.x; acc[1] += sg * e0.y;
    acc[2] += sg * e0.z; acc[3] += sg * e0.w;
    acc[4] += sg * e1.x; acc[5] += sg * e1.y;
    acc[6] += sg * e1.z; acc[7] += sg * e1.w;
  }
  *(float4*)&pad[wave][lane * 8] = *(float4*)&acc[0];
  *(float4*)&pad[wave][lane * 8 + 4] = *(float4*)&acc[4];
  if (lane == 0) wsum[wave] = csum;
  __syncthreads();
  float* o = pctx + ((size_t)b * NCH + chunk) * Hdim;
  o[tid] = pad[0][tid] + pad[1][tid] + pad[2][tid] + pad[3][tid];
  o[tid + 256] = pad[0][tid + 256] + pad[1][tid + 256] + pad[2][tid + 256] + pad[3][tid + 256];
  if (tid == 0) atomicAdd(ssum_cur + b, wsum[0] + wsum[1] + wsum[2] + wsum[3]);
}

// ---------------------------------------------------------------- ctx reduce + hcat row
__global__ __launch_bounds__(256) void k_hcat(
    const float* __restrict__ h, const float* __restrict__ pctx,
    const float* __restrict__ ssum, float* __restrict__ hcat) {
  __shared__ float4 red[256];
  const int b = blockIdx.x;
  const int tid = threadIdx.x;
  const float inv = 1.0f / ssum[b];
  const float4* p4 = (const float4*)(pctx + (size_t)b * NCH * Hdim);
  const int q = tid & 127, ch0 = tid >> 7;
  float4 a = {0.f, 0.f, 0.f, 0.f};
  for (int ch = ch0; ch < NCH; ch += 2) {
    float4 v = p4[ch * 128 + q];
    a.x += v.x; a.y += v.y; a.z += v.z; a.w += v.w;
  }
  red[tid] = a;
  hcat[(size_t)b * 1024 + tid] = h[(size_t)b * Hdim + tid];
  hcat[(size_t)b * 1024 + tid + 256] = h[(size_t)b * Hdim + tid + 256];
  __syncthreads();
  if (tid < 128) {
    float4 r0 = red[tid], r1 = red[tid + 128];
    float4 c4 = {(r0.x + r1.x) * inv, (r0.y + r1.y) * inv,
                 (r0.z + r1.z) * inv, (r0.w + r1.w) * inv};
    *(float4*)&hcat[(size_t)b * 1024 + 512 + q * 4] = c4;
  }
}

// ---------------------------------------------------------------- output head
__global__ __launch_bounds__(256) void k_out2(
    const float* __restrict__ co, const float* __restrict__ WoT,
    const float* __restrict__ b_out, const int* __restrict__ labels, int t,
    int* __restrict__ curin, float* __restrict__ lossb, float* __restrict__ d_out) {
  __shared__ float cs[512];
  const int b = blockIdx.x;
  const int tid = threadIdx.x;
  cs[tid] = co[(size_t)b * Hdim + tid];
  cs[tid + 256] = co[(size_t)b * Hdim + tid + 256];
  __syncthreads();
  if (tid < 64) {
    float l0 = 0.f, l1 = 0.f, l2 = 0.f, l3 = 0.f;
    for (int k = 0; k < 512; k += 4) {
      l0 += cs[k] * WoT[(size_t)k * 64 + tid];
      l1 += cs[k + 1] * WoT[(size_t)(k + 1) * 64 + tid];
      l2 += cs[k + 2] * WoT[(size_t)(k + 2) * 64 + tid];
      l3 += cs[k + 3] * WoT[(size_t)(k + 3) * 64 + tid];
    }
    const float lg = ((l0 + l1) + (l2 + l3)) + b_out[tid];
    float mx = lg;
    int mi = tid;
#pragma unroll
    for (int off = 32; off; off >>= 1) {
      float ov = __shfl_xor(mx, off, 64);
      int oi = __shfl_xor(mi, off, 64);
      if (ov > mx || (ov == mx && oi < mi)) { mx = ov; mi = oi; }
    }
    float se = __expf(lg - mx);
#pragma unroll
    for (int off = 32; off; off >>= 1) se += __shfl_xor(se, off, 64);
    const int lab = labels[t * Bdim + b];
    const float lg_lab = __shfl(lg, lab, 64);
    if (tid == 0) {
      const float ce = -(lg_lab - mx - __logf(se));
      atomicAdd(lossb, ce * (1.0f / 32.0f));
      curin[b] = mi;
      d_out[1 + b * Tdim + t] = (float)mi;
    }
  }
}

__global__ void k_final(const float* __restrict__ lossb, float* __restrict__ d_out) {
  if (threadIdx.x == 0) d_out[0] = lossb[0];
}

// ---------------------------------------------------------------- launch
extern "C" void kernel_launch(void* const* d_in, const int* in_sizes, int n_in,
                              void* d_out, int out_size, void* d_ws, size_t ws_size,
                              hipStream_t stream) {
  const int* init_in = (const int*)d_in[0];
  const float* h0 = (const float*)d_in[1];
  const float* c0 = (const float*)d_in[2];
  const float* enc = (const float*)d_in[3];
  const int* labels = (const int*)d_in[4];
  const float* embed = (const float*)d_in[7];
  const float* W_ih = (const float*)d_in[8];
  const float* W_hh = (const float*)d_in[9];
  const float* b_ih = (const float*)d_in[10];
  const float* b_hh = (const float*)d_in[11];
  const float* W_concat = (const float*)d_in[12];
  const float* b_concat = (const float*)d_in[13];
  const float* W_out = (const float*)d_in[14];
  const float* b_out = (const float*)d_in[15];
  const float* conv_w = (const float*)d_in[16];
  const float* conv_b = (const float*)d_in[17];
  const float* Wq = (const float*)d_in[18];
  const float* Wv = (const float*)d_in[19];
  const float* Ws_ = (const float*)d_in[20];
  const float* bs = (const float*)d_in[21];
  const float* attn_bias = (const float*)d_in[22];
  float* out = (float*)d_out;

  // VE layout needs B*L*1024 floats (268MB) + ~8MB tail
  const size_t ve_floats = (size_t)Bdim * Ldim * 1024;
  const size_t tail_floats = 4u * 1024 * 1024;
  const bool useVE = ws_size >= (ve_floats + tail_floats) * sizeof(float);

  float* ws = (float*)d_ws;
  size_t off = 0;
  auto alloc = [&](size_t n) {
    float* p = ws + off;
    off += (n + 63) & ~(size_t)63;
    return p;
  };
  float* big = alloc(useVE ? ve_floats : (size_t)Bdim * Ldim * Hdim);
  float* embW = alloc(Vdim * 2048);
  float* WoT = alloc(512 * 64);
  float* P4b = alloc(512 * 4);
  float* cbab = alloc(512);
  float* hA = alloc(Bdim * Hdim);
  float* hB = alloc(Bdim * Hdim);
  float* cbuf = alloc(Bdim * Hdim);
  float* q2 = alloc(Bdim * Hdim);
  float* S0 = alloc(Bdim * Ldim);
  float* S1 = alloc(Bdim * Ldim);
  float* ssum = alloc(64);                          // [2][32]
  float* pctx = alloc((size_t)Bdim * NCH * Hdim);   // [b][ch][h]
  float* hcatb = alloc(Bdim * 1024);
  float* cob = alloc(Bdim * Hdim);
  float* lossb = alloc(64);
  int* curin = (int*)alloc(64);
  (void)in_sizes; (void)n_in; (void)out_size;

  // one-time setup
  k_init<<<256, 256, 0, stream>>>(init_in, h0, c0, hA, cbuf, S1, ssum, curin, lossb);
  k_pack<<<2, 256, 0, stream>>>(conv_w, conv_b, attn_bias, Ws_, (float4*)P4b, cbab);
  k_transpose<<<(64 * 512 + 255) / 256, 256, 0, stream>>>(W_out, WoT, 64, 512);
  k_matT16<<<dim3(128, 2), 256, 0, stream>>>(embed, W_ih, embW, 512, 2048, 2,
                                             b_ih, b_hh);
  k_vproj<<<dim3(512, 4), 256, 0, stream>>>(enc, Wv, big, useVE ? 1024 : 512);
  if (useVE) k_copyenc<<<Bdim * Ldim, 128, 0, stream>>>(enc, big);

  for (int t = 0; t < Tdim; t++) {
    const int cur = t & 1;
    float* Scur = cur ? S1 : S0;
    float* Sprev = cur ? S0 : S1;
    float* hprev = cur ? hB : hA;
    float* hnew = cur ? hA : hB;
    float* ssum_cur = ssum + cur * 32;
    float* ssum_prev = ssum + (cur ^ 1) * 32;
    k_gatecell<<<32, 256, 0, stream>>>(hprev, W_hh, embW, curin, hnew, cbuf, ssum_cur);
    k_matT16<<<dim3(32, 1), 256, 0, stream>>>(hnew, Wq, q2, 512, 512, 1,
                                              cbab, nullptr);
    k_sctx<<<Bdim * NCH, 256, 0, stream>>>(big, enc, q2, Sprev, ssum_prev,
                                           (const float4*)P4b, bs, Scur, ssum_cur,
                                           pctx, useVE ? 1 : 0);
    k_hcat<<<32, 256, 0, stream>>>(hnew, pctx, ssum_cur, hcatb);
    k_matT16<<<dim3(32, 1), 256, 0, stream>>>(hcatb, W_concat, cob, 1024, 512, 3,
                                              b_concat, nullptr);
    k_out2<<<32, 256, 0, stream>>>(cob, WoT, b_out, labels, t, curin, lossb, out);
  }
  k_final<<<1, 64, 0, stream>>>(lossb, out);
}

// Round 7
// 4967.023 us; speedup vs baseline: 1.3130x; 1.3130x over previous
//
#include <hip/hip_runtime.h>
#include <math.h>

// Seq2seq decoder w/ location-aware attention. H=512 V=64 B=32 L=2048 T=32.
// All f32 (greedy argmax feedback must track numpy; bf16 flips preds -> fail).
//
// R7 = R5 structure (proven 5303us) + fused tail kernel k_head.
//   R6 regression attributed to k_gatecell (32-blk LDS-bound) -> reverted.
// Per step (5 kernels):
//  1 k_matT16 m0 (128 blk): gates = hprev @ W_hh^T + embW[curin]
//  2 k_cell   (64 blk):     LSTM cell -> hnew, cbuf; zeroes ssum_cur
//  3 k_matT16 m1 (32 blk):  q2 = hnew @ Wq^T + (conv_b+attn_bias)
//  4 k_sctx   (2048 blk):   per (b,32-l chunk): score->Scur + partial ctx
//  5 k_head   (32 blk):     ctx reduce + co=tanh([h|ctx]@Wc^T+b) (split-K over
//                           WcT, L2-served) + logits/softmax/argmax/CE
// One-time: embW = emb@W_ih^T+b_ih+b_hh, WoT, WcT, pack, v_proj.

#define Hdim 512
#define Vdim 64
#define Bdim 32
#define Ldim 2048
#define Tdim 32
#define CLEN 32
#define NCH 64

__device__ __forceinline__ float sigmoid_f(float x) {
  return 1.0f / (1.0f + __expf(-x));
}
__device__ __forceinline__ float tanh_f(float x) {
  float ax = fabsf(x);
  float e = __expf(2.0f * ax);
  float r = 1.0f - 2.0f / (e + 1.0f);
  return copysignf(r, x);
}

// ---------------------------------------------------------------- init
__global__ void k_init(const int* __restrict__ init_in, const float* __restrict__ h0,
                       const float* __restrict__ c0, float* __restrict__ h,
                       float* __restrict__ c, float* __restrict__ Sprev,
                       float* __restrict__ ssum, int* __restrict__ curin,
                       float* __restrict__ lossb) {
  int i = blockIdx.x * blockDim.x + threadIdx.x;
  if (i < Bdim * Hdim) { h[i] = h0[i]; c[i] = c0[i]; }
  if (i < Bdim * Ldim) Sprev[i] = 0.0f;
  if (i < Bdim) { ssum[32 + i] = 1.0f; curin[i] = init_in[i]; }
  if (i == 0) lossb[0] = 0.0f;
}

__global__ void k_pack(const float* __restrict__ conv_w, const float* __restrict__ conv_b,
                       const float* __restrict__ attn_bias, const float* __restrict__ Ws,
                       float4* __restrict__ P4, float* __restrict__ cbab) {
  int h = blockIdx.x * blockDim.x + threadIdx.x;
  if (h < Hdim) {
    P4[h] = make_float4(conv_w[3 * h], conv_w[3 * h + 1], conv_w[3 * h + 2], Ws[h]);
    cbab[h] = conv_b[h] + attn_bias[h];
  }
}

__global__ void k_transpose(const float* __restrict__ in, float* __restrict__ out,
                            int R, int C) {
  int i = blockIdx.x * blockDim.x + threadIdx.x;
  if (i < R * C) { int r = i / C, c = i % C; out[(size_t)c * R + r] = in[i]; }
}

// ---------------------------------------------------------------- 32m x 16n GEMM
// m0: +embW[curin[m]*2048+n]  m1: +ex1[n]  m2: +ex1[n]+ex2[n]  m3: tanh(+ex1[n])
__global__ __launch_bounds__(256) void k_matT16(
    const float* __restrict__ A, const float* __restrict__ W,
    float* __restrict__ out, int Kdim, int Ntot, int mode,
    const int* __restrict__ curin, const float* __restrict__ ex1,
    const float* __restrict__ ex2) {
  __shared__ float a_lds[64][33];
  __shared__ float w_lds[64][17];
  const int tid = threadIdx.x;
  const int n0 = blockIdx.x * 16;
  const int m0 = blockIdx.y * 32;
  const int tm = tid >> 3;
  const int tn = tid & 7;
  float acc0 = 0.f, acc1 = 0.f;
  for (int k0 = 0; k0 < Kdim; k0 += 64) {
    {
      const int m = tid & 31, kg = tid >> 5;
      const float* ap = A + (size_t)(m0 + m) * Kdim + k0 + kg * 8;
      float4 v0 = *(const float4*)ap;
      float4 v1 = *(const float4*)(ap + 4);
      const int kk = kg * 8;
      a_lds[kk + 0][m] = v0.x; a_lds[kk + 1][m] = v0.y;
      a_lds[kk + 2][m] = v0.z; a_lds[kk + 3][m] = v0.w;
      a_lds[kk + 4][m] = v1.x; a_lds[kk + 5][m] = v1.y;
      a_lds[kk + 6][m] = v1.z; a_lds[kk + 7][m] = v1.w;
    }
    if (tid < 128) {
      const int r = tid & 15, kg = tid >> 4;
      const float* wp = W + (size_t)(n0 + r) * Kdim + k0 + kg * 8;
      float4 v0 = *(const float4*)wp;
      float4 v1 = *(const float4*)(wp + 4);
      const int kk = kg * 8;
      w_lds[kk + 0][r] = v0.x; w_lds[kk + 1][r] = v0.y;
      w_lds[kk + 2][r] = v0.z; w_lds[kk + 3][r] = v0.w;
      w_lds[kk + 4][r] = v1.x; w_lds[kk + 5][r] = v1.y;
      w_lds[kk + 6][r] = v1.z; w_lds[kk + 7][r] = v1.w;
    }
    __syncthreads();
#pragma unroll 16
    for (int kk = 0; kk < 64; kk++) {
      const float a = a_lds[kk][tm];
      acc0 += a * w_lds[kk][tn * 2];
      acc1 += a * w_lds[kk][tn * 2 + 1];
    }
    __syncthreads();
  }
  const int gm = m0 + tm;
#pragma unroll
  for (int c = 0; c < 2; c++) {
    const int n = n0 + tn * 2 + c;
    const float a = (c == 0) ? acc0 : acc1;
    float r;
    if (mode == 0)      r = a + ex1[(size_t)curin[gm] * 2048 + n];
    else if (mode == 1) r = a + ex1[n];
    else if (mode == 2) r = a + ex1[n] + ex2[n];
    else                r = tanh_f(a + ex1[n]);
    out[(size_t)gm * Ntot + n] = r;
  }
}

// ---------------------------------------------------------------- v_proj GEMM
__global__ __launch_bounds__(256) void k_vproj(const float* __restrict__ enc,
                                               const float* __restrict__ Wv,
                                               float* __restrict__ vp) {
  __shared__ float At[8][128];
  __shared__ float Bt[8][128];
  const int tid = threadIdx.x;
  const int r0 = blockIdx.x * 128;
  const int c0 = blockIdx.y * 128;
  const int tx = tid & 15;
  const int ty = tid >> 4;
  float acc[8][8];
#pragma unroll
  for (int i = 0; i < 8; i++)
#pragma unroll
    for (int j = 0; j < 8; j++) acc[i][j] = 0.f;

  for (int k0 = 0; k0 < Hdim; k0 += 8) {
    {
      const int r = tid & 127;
      const int kg = tid >> 7;
      const int gr = r0 + r;
      const int b = gr >> 11;
      const int l = gr & (Ldim - 1);
      const float* ap = enc + ((size_t)l * Bdim + b) * Hdim + k0 + kg * 4;
      float4 v = *(const float4*)ap;
      At[kg * 4 + 0][r] = v.x; At[kg * 4 + 1][r] = v.y;
      At[kg * 4 + 2][r] = v.z; At[kg * 4 + 3][r] = v.w;
      const float* wp = Wv + (size_t)(c0 + r) * Hdim + k0 + kg * 4;
      float4 w = *(const float4*)wp;
      Bt[kg * 4 + 0][r] = w.x; Bt[kg * 4 + 1][r] = w.y;
      Bt[kg * 4 + 2][r] = w.z; Bt[kg * 4 + 3][r] = w.w;
    }
    __syncthreads();
#pragma unroll
    for (int kk = 0; kk < 8; kk++) {
      float a[8], bb[8];
      *(float4*)&a[0] = *(const float4*)&At[kk][ty * 8];
      *(float4*)&a[4] = *(const float4*)&At[kk][ty * 8 + 4];
      *(float4*)&bb[0] = *(const float4*)&Bt[kk][tx * 4];
      *(float4*)&bb[4] = *(const float4*)&Bt[kk][64 + tx * 4];
#pragma unroll
      for (int i = 0; i < 8; i++)
#pragma unroll
        for (int j = 0; j < 8; j++) acc[i][j] += a[i] * bb[j];
    }
    __syncthreads();
  }
#pragma unroll
  for (int i = 0; i < 8; i++) {
    float* orow = vp + (size_t)(r0 + ty * 8 + i) * Hdim + c0;
    float4 o0 = {acc[i][0], acc[i][1], acc[i][2], acc[i][3]};
    float4 o1 = {acc[i][4], acc[i][5], acc[i][6], acc[i][7]};
    *(float4*)(orow + tx * 4) = o0;
    *(float4*)(orow + 64 + tx * 4) = o1;
  }
}

// ---------------------------------------------------------------- LSTM cell (+zero ssum_cur)
__global__ void k_cell(const float* __restrict__ gates, float* __restrict__ h,
                       float* __restrict__ c, float* __restrict__ ssum_cur) {
  int i = blockIdx.x * blockDim.x + threadIdx.x;
  if (blockIdx.x == 0 && threadIdx.x < Bdim) ssum_cur[threadIdx.x] = 0.f;
  int b = i >> 9, hh = i & 511;
  const float* g = gates + (size_t)b * 2048;
  float gi = g[hh], gf = g[512 + hh], gg = g[1024 + hh], go = g[1536 + hh];
  float cn = sigmoid_f(gf) * c[i] + sigmoid_f(gi) * tanh_f(gg);
  float hn = sigmoid_f(go) * tanh_f(cn);
  c[i] = cn;
  h[i] = hn;
}

// ---------------------------------------------------------------- fused score+ctx sweep
__global__ __launch_bounds__(256) void k_sctx(
    const float* __restrict__ vp, const float* __restrict__ q2,
    const float* __restrict__ Sprev, const float* __restrict__ ssum_prev,
    const float4* __restrict__ P4, const float* __restrict__ bs,
    const float* __restrict__ enc, float* __restrict__ Scur,
    float* __restrict__ ssum_cur, float* __restrict__ pctx) {
  __shared__ float pad[4][512];
  __shared__ float wsum[4];
  const int chunk = blockIdx.x & (NCH - 1);
  const int b = blockIdx.x >> 6;
  const int tid = threadIdx.x;
  const int wave = tid >> 6, lane = tid & 63;
  const int l0 = chunk * CLEN + wave * 8;

  float4 pp[8];
#pragma unroll
  for (int e = 0; e < 8; e++) pp[e] = P4[lane * 8 + e];
  float qv[8];
  {
    const float* qrow = q2 + (size_t)b * Hdim + lane * 8;
    *(float4*)&qv[0] = *(const float4*)qrow;
    *(float4*)&qv[4] = *(const float4*)(qrow + 4);
  }
  const float inv = 1.0f / ssum_prev[b];
  const float* sp = Sprev + (size_t)b * Ldim;
  const float bsv = bs[0];

  float acc[8];
#pragma unroll
  for (int e = 0; e < 8; e++) acc[e] = 0.f;
  float csum = 0.f;

#pragma unroll 2
  for (int i = 0; i < 8; i++) {
    const int l = l0 + i;
    const float* vrow = vp + ((size_t)b * Ldim + l) * Hdim + lane * 8;
    const float* erow = enc + ((size_t)l * Bdim + b) * Hdim + lane * 8;
    float vv[8];
    *(float4*)&vv[0] = *(const float4*)vrow;
    *(float4*)&vv[4] = *(const float4*)(vrow + 4);
    const float4 e0 = *(const float4*)erow;
    const float4 e1 = *(const float4*)(erow + 4);
    const float a0 = (l > 0) ? sp[l - 1] * inv : 0.f;
    const float a1 = sp[l] * inv;
    const float a2 = (l < Ldim - 1) ? sp[l + 1] * inv : 0.f;
    float s = 0.f;
#pragma unroll
    for (int e = 0; e < 8; e++) {
      float x = vv[e] + qv[e] + pp[e].x * a0 + pp[e].y * a1 + pp[e].z * a2;
      s += pp[e].w * tanh_f(x);
    }
#pragma unroll
    for (int off = 32; off; off >>= 1) s += __shfl_xor(s, off, 64);
    const float sg = 1.0f / (1.0f + __expf(-(s + bsv)));
    csum += sg;
    if (lane == 0) Scur[(size_t)b * Ldim + l] = sg;
    acc[0] += sg * e0.x; acc[1] += sg * e0.y;
    acc[2] += sg * e0.z; acc[3] += sg * e0.w;
    acc[4] += sg * e1.x; acc[5] += sg * e1.y;
    acc[6] += sg * e1.z; acc[7] += sg * e1.w;
  }
  *(float4*)&pad[wave][lane * 8] = *(float4*)&acc[0];
  *(float4*)&pad[wave][lane * 8 + 4] = *(float4*)&acc[4];
  if (lane == 0) wsum[wave] = csum;
  __syncthreads();
  float* o = pctx + ((size_t)b * NCH + chunk) * Hdim;
  o[tid] = pad[0][tid] + pad[1][tid] + pad[2][tid] + pad[3][tid];
  o[tid + 256] = pad[0][tid + 256] + pad[1][tid + 256] + pad[2][tid + 256] + pad[3][tid + 256];
  if (tid == 0) atomicAdd(ssum_cur + b, wsum[0] + wsum[1] + wsum[2] + wsum[3]);
}

// ---------------------------------------------------------------- fused tail: ctx reduce +
// co = tanh([h|ctx] @ W_concat^T + b_concat) (split-K over WcT) + logits/argmax/CE.
// One block per b; WcT (2MB) is shared by all 32 blocks -> per-XCD L2 resident.
__global__ __launch_bounds__(256) void k_head(
    const float* __restrict__ h, const float* __restrict__ pctx,
    const float* __restrict__ ssum, const float* __restrict__ WcT,
    const float* __restrict__ b_concat, const float* __restrict__ WoT,
    const float* __restrict__ b_out, const int* __restrict__ labels, int t,
    int* __restrict__ curin, float* __restrict__ lossb, float* __restrict__ d_out) {
  __shared__ float hcat[1024];
  __shared__ float part[2][512];
  __shared__ float co[512];
  const int b = blockIdx.x;
  const int tid = threadIdx.x;
  const float inv = 1.0f / ssum[b];
  // phase 1: ctx reduce over 64 chunks (serial, deterministic), build hcat
  {
    float c0 = 0.f, c1 = 0.f;
    const float* p = pctx + (size_t)b * NCH * Hdim;
#pragma unroll 8
    for (int ch = 0; ch < NCH; ch++) {
      c0 += p[(size_t)ch * Hdim + tid];
      c1 += p[(size_t)ch * Hdim + tid + 256];
    }
    hcat[tid] = h[(size_t)b * Hdim + tid];
    hcat[tid + 256] = h[(size_t)b * Hdim + tid + 256];
    hcat[512 + tid] = c0 * inv;
    hcat[512 + tid + 256] = c1 * inv;
  }
  __syncthreads();
  // phase 2: split-K co GEMM.  waves 0-1: k 0..511, waves 2-3: k 512..1023.
  {
    const int half = tid >> 7;
    const int c4 = (tid & 127) * 4;
    float4 a4 = {0.f, 0.f, 0.f, 0.f};
    const float* wbase = WcT + (size_t)half * 512 * 512 + c4;
    const float* hb = &hcat[half * 512];
    for (int k = 0; k < 512; k++) {
      const float a = hb[k];
      const float4 w = *(const float4*)(wbase + (size_t)k * 512);
      a4.x += a * w.x; a4.y += a * w.y; a4.z += a * w.z; a4.w += a * w.w;
    }
    *(float4*)&part[half][c4] = a4;
  }
  __syncthreads();
  co[tid] = tanh_f(part[0][tid] + part[1][tid] + b_concat[tid]);
  co[tid + 256] = tanh_f(part[0][tid + 256] + part[1][tid + 256] + b_concat[tid + 256]);
  __syncthreads();
  // phase 3: logits + softmax + argmax + CE (wave 0, lane = vocab id)
  if (tid < 64) {
    float l0 = 0.f, l1 = 0.f, l2 = 0.f, l3 = 0.f;
    for (int k = 0; k < 512; k += 4) {
      l0 += co[k] * WoT[(size_t)k * 64 + tid];
      l1 += co[k + 1] * WoT[(size_t)(k + 1) * 64 + tid];
      l2 += co[k + 2] * WoT[(size_t)(k + 2) * 64 + tid];
      l3 += co[k + 3] * WoT[(size_t)(k + 3) * 64 + tid];
    }
    const float lg = ((l0 + l1) + (l2 + l3)) + b_out[tid];
    float mx = lg;
    int mi = tid;
#pragma unroll
    for (int off = 32; off; off >>= 1) {
      float ov = __shfl_xor(mx, off, 64);
      int oi = __shfl_xor(mi, off, 64);
      if (ov > mx || (ov == mx && oi < mi)) { mx = ov; mi = oi; }
    }
    float se = __expf(lg - mx);
#pragma unroll
    for (int off = 32; off; off >>= 1) se += __shfl_xor(se, off, 64);
    const int lab = labels[t * Bdim + b];
    const float lg_lab = __shfl(lg, lab, 64);
    if (tid == 0) {
      const float ce = -(lg_lab - mx - __logf(se));
      atomicAdd(lossb, ce * (1.0f / 32.0f));
      curin[b] = mi;
      d_out[1 + b * Tdim + t] = (float)mi;
    }
  }
}

__global__ void k_final(const float* __restrict__ lossb, float* __restrict__ d_out) {
  if (threadIdx.x == 0) d_out[0] = lossb[0];
}

// ---------------------------------------------------------------- launch
extern "C" void kernel_launch(void* const* d_in, const int* in_sizes, int n_in,
                              void* d_out, int out_size, void* d_ws, size_t ws_size,
                              hipStream_t stream) {
  const int* init_in = (const int*)d_in[0];
  const float* h0 = (const float*)d_in[1];
  const float* c0 = (const float*)d_in[2];
  const float* enc = (const float*)d_in[3];
  const int* labels = (const int*)d_in[4];
  const float* embed = (const float*)d_in[7];
  const float* W_ih = (const float*)d_in[8];
  const float* W_hh = (const float*)d_in[9];
  const float* b_ih = (const float*)d_in[10];
  const float* b_hh = (const float*)d_in[11];
  const float* W_concat = (const float*)d_in[12];
  const float* b_concat = (const float*)d_in[13];
  const float* W_out = (const float*)d_in[14];
  const float* b_out = (const float*)d_in[15];
  const float* conv_w = (const float*)d_in[16];
  const float* conv_b = (const float*)d_in[17];
  const float* Wq = (const float*)d_in[18];
  const float* Wv = (const float*)d_in[19];
  const float* Ws_ = (const float*)d_in[20];
  const float* bs = (const float*)d_in[21];
  const float* attn_bias = (const float*)d_in[22];
  float* out = (float*)d_out;

  float* ws = (float*)d_ws;
  size_t off = 0;
  auto alloc = [&](size_t n) {
    float* p = ws + off;
    off += (n + 63) & ~(size_t)63;
    return p;
  };
  float* vp = alloc((size_t)Bdim * Ldim * Hdim);   // 134 MB
  float* embW = alloc(Vdim * 2048);
  float* WoT = alloc(512 * 64);
  float* WcT = alloc(1024 * 512);                   // 2 MB
  float* P4b = alloc(512 * 4);
  float* cbab = alloc(512);
  float* gates = alloc(Bdim * 2048);
  float* hA = alloc(Bdim * Hdim);
  float* hB = alloc(Bdim * Hdim);
  float* cbuf = alloc(Bdim * Hdim);
  float* q2 = alloc(Bdim * Hdim);
  float* S0 = alloc(Bdim * Ldim);
  float* S1 = alloc(Bdim * Ldim);
  float* ssum = alloc(64);                          // [2][32]
  float* pctx = alloc((size_t)Bdim * NCH * Hdim);   // [b][ch][h], 4.2 MB
  float* lossb = alloc(64);
  int* curin = (int*)alloc(64);
  (void)ws_size; (void)in_sizes; (void)n_in; (void)out_size;

  // one-time setup
  k_init<<<256, 256, 0, stream>>>(init_in, h0, c0, hA, cbuf, S1, ssum, curin, lossb);
  k_pack<<<2, 256, 0, stream>>>(conv_w, conv_b, attn_bias, Ws_, (float4*)P4b, cbab);
  k_transpose<<<(64 * 512 + 255) / 256, 256, 0, stream>>>(W_out, WoT, 64, 512);
  k_transpose<<<(512 * 1024 + 255) / 256, 256, 0, stream>>>(W_concat, WcT, 512, 1024);
  k_matT16<<<dim3(128, 2), 256, 0, stream>>>(embed, W_ih, embW, 512, 2048, 2,
                                             nullptr, b_ih, b_hh);
  k_vproj<<<dim3(512, 4), 256, 0, stream>>>(enc, Wv, vp);

  for (int t = 0; t < Tdim; t++) {
    const int cur = t & 1;
    float* Scur = cur ? S1 : S0;
    float* Sprev = cur ? S0 : S1;
    float* hprev = cur ? hB : hA;
    float* hnew = cur ? hA : hB;
    float* ssum_cur = ssum + cur * 32;
    float* ssum_prev = ssum + (cur ^ 1) * 32;
    k_matT16<<<dim3(128, 1), 256, 0, stream>>>(hprev, W_hh, gates, 512, 2048, 0,
                                               curin, embW, nullptr);
    k_cell<<<64, 256, 0, stream>>>(gates, hnew, cbuf, ssum_cur);
    k_matT16<<<dim3(32, 1), 256, 0, stream>>>(hnew, Wq, q2, 512, 512, 1,
                                              nullptr, cbab, nullptr);
    k_sctx<<<Bdim * NCH, 256, 0, stream>>>(vp, q2, Sprev, ssum_prev, (const float4*)P4b,
                                           bs, enc, Scur, ssum_cur, pctx);
    k_head<<<32, 256, 0, stream>>>(hnew, pctx, ssum_cur, WcT, b_concat, WoT, b_out,
                                   labels, t, curin, lossb, out);
  }
  k_final<<<1, 64, 0, stream>>>(lossb, out);
}